// Round 1
// baseline (1482.216 us; speedup 1.0000x reference)
//
#include <hip/hip_runtime.h>
#include <hip/hip_bf16.h>

// Problem constants (from setup_inputs / reference)
#define BH 120
#define BW 240
#define NLVL 5
#define NCAM 6
#define CH 128          // cam feature channels
#define FH 64           // cam feature H
#define FW 176          // cam feature W
#define CIN 655         // (128+3)*5
#define PADH 122
#define PADW 242
#define PLANE (PADH*PADW)   // 29524
#define NPIX (BH*BW)        // 28800

// ---------------------------------------------------------------------------
// Kernel T: transpose cam_feat [6][128][64][176] f32 -> camt [6][64][176][128]
// so that per-tap channel gathers in proj are contiguous 512B reads.
// ---------------------------------------------------------------------------
__global__ __launch_bounds__(256) void transpose_kernel(
    const float* __restrict__ in, float* __restrict__ out)
{
    __shared__ float t[32][129];
    int n = blockIdx.z, h = blockIdx.y, w0 = blockIdx.x * 32;
    int wlim = min(32, FW - w0);
    int wx = threadIdx.x & 31, cg = threadIdx.x >> 5;   // cg in 0..7
    if (wx < wlim) {
        #pragma unroll
        for (int k = 0; k < 16; ++k) {
            int c = cg + k * 8;
            t[wx][c] = in[((n*CH + c)*FH + h)*FW + w0 + wx];
        }
    }
    __syncthreads();
    int c2 = threadIdx.x & 127, wi = threadIdx.x >> 7;  // wi in 0..1
    for (int w = wi; w < wlim; w += 2) {
        out[((n*FH + h)*FW + w0 + w)*CH + c2] = t[w][c2];
    }
}

// ---------------------------------------------------------------------------
// Kernel Z: zero the 1-pixel border of every padded feat plane.
// ---------------------------------------------------------------------------
__global__ __launch_bounds__(256) void border_kernel(float* __restrict__ feat)
{
    int cin = blockIdx.x;
    float* p = feat + (size_t)cin * PLANE;
    for (int t = threadIdx.x; t < 724; t += 256) {
        int idx;
        if (t < 242)       idx = t;                         // row 0
        else if (t < 484)  idx = 121*PADW + (t - 242);      // row 121
        else if (t < 604)  idx = (t - 484 + 1)*PADW;        // col 0, rows 1..120
        else               idx = (t - 604 + 1)*PADW + 241;  // col 241
        p[idx] = 0.f;
    }
}

// ---------------------------------------------------------------------------
// Kernel P: per BEV pixel (by,bx): project 5 levels x 6 cams, bilinear-sample
// 128 channels from camt, average over valid cams, write padded feat
// [655][122][242] (cin = ch*5 + lvl), plus the 15 coord channels.
// Block = 128 threads (thread = channel). Projection math done by lanes 0..29.
// ---------------------------------------------------------------------------
__global__ __launch_bounds__(128) void proj_kernel(
    const float* __restrict__ camt,
    const float* __restrict__ e2c,      // [6][16]
    const int* __restrict__ pimgh, const int* __restrict__ pimgw,
    float* __restrict__ feat)
{
    __shared__ float sfx[30], sfy[30];
    __shared__ int   six[30], siy[30], svalid[30];

    int pix = blockIdx.x;
    int bx = pix % BW, by = pix / BW;
    float xw = (float)(-30.0 + bx * (60.0/239.0)); if (bx == BW-1) xw = 30.f;
    float yw = (float)(-15.0 + by * (30.0/119.0)); if (by == BH-1) yw = 15.f;

    int t = threadIdx.x;
    if (t < 30) {
        int l = t / 6, cam = t % 6;
        float h = -1.f + 0.5f * (float)l;
        const float* M = e2c + cam * 16;
        float cx = M[0]*xw + M[1]*yw + M[2]*h  + M[3];
        float cy = M[4]*xw + M[5]*yw + M[6]*h  + M[7];
        float cz = M[8]*xw + M[9]*yw + M[10]*h + M[11];
        float fw = (float)pimgw[0], fh = (float)pimgh[0];
        float px = ((cx/cz + 1e-9f)/fw - 0.5f) * 2.f;
        float py = ((cy/cz + 1e-9f)/fh - 0.5f) * 2.f;
        bool valid = (cz > 1e-9f) && (px > -1.f) && (px < 1.f)
                                  && (py > -1.f) && (py < 1.f);
        float xs = ((px + 1.f)*(float)FW - 1.f) * 0.5f;
        float ys = ((py + 1.f)*(float)FH - 1.f) * 0.5f;
        float x0 = floorf(xs), y0 = floorf(ys);
        sfx[t] = xs - x0;  sfy[t] = ys - y0;
        six[t] = (int)x0;  siy[t] = (int)y0;
        svalid[t] = valid ? 1 : 0;
    }
    __syncthreads();

    int c = t;   // channel 0..127
    float vals[NLVL];
    #pragma unroll
    for (int l = 0; l < NLVL; ++l) {
        float acc = 0.f; int cnt = 0;
        #pragma unroll
        for (int cam = 0; cam < NCAM; ++cam) {
            int id = l*6 + cam;
            if (svalid[id]) {           // block-uniform branch
                int ix = six[id], iy = siy[id];      // in [-1,175], [-1,63]
                float fx = sfx[id], fy = sfy[id];
                const float* bp = camt + (((size_t)cam*FH + iy)*FW + ix)*CH + c;
                float v00 = (ix >= 0    && iy >= 0   ) ? bp[0]        : 0.f;
                float v01 = (ix >= 0    && iy <  FH-1) ? bp[FW*CH]    : 0.f;
                float v10 = (ix <  FW-1 && iy >= 0   ) ? bp[CH]       : 0.f;
                float v11 = (ix <  FW-1 && iy <  FH-1) ? bp[FW*CH+CH] : 0.f;
                acc += (1.f-fx)*(1.f-fy)*v00 + (1.f-fx)*fy*v01
                     +      fx *(1.f-fy)*v10 +      fx *fy*v11;
                cnt++;
            }
        }
        vals[l] = acc / (float)(cnt > 0 ? cnt : 1);
    }

    float* dst = feat + (size_t)(by+1)*PADW + (bx+1);
    #pragma unroll
    for (int l = 0; l < NLVL; ++l)
        dst[(size_t)(c*5 + l)*PLANE] = vals[l];
    if (t < 15) {               // coord channels: cin = (128+j)*5 + l
        int j = t / 5, l = t % 5;
        float v = (j == 0) ? xw : (j == 1) ? yw : (-1.f + 0.5f*(float)l);
        dst[(size_t)((CH + j)*5 + l)*PLANE] = v;
    }
}

// ---------------------------------------------------------------------------
// Kernel C: direct 3x3 conv, f32 vector ALU.
// Tile: 16 oc x (8 rows x 32 cols). Per-cin: stage 10x34 input halo in LDS,
// weights read via block-uniform (scalar) loads. Grid (8 ct, 15 rt, 8 ocg).
// ---------------------------------------------------------------------------
__global__ __launch_bounds__(256) void conv_kernel(
    const float* __restrict__ feat,     // [655][122][242] padded
    const float* __restrict__ w,        // [128][655][3][3]
    const float* __restrict__ bias,     // [128]
    float* __restrict__ out)            // [128][120][240]
{
    __shared__ float tile[10][36];
    int cx = threadIdx.x & 31, r = threadIdx.x >> 5;
    int x0 = blockIdx.x * 32, y0 = blockIdx.y * 8, oc0 = blockIdx.z * 16;

    float acc[16];
    #pragma unroll
    for (int o = 0; o < 16; ++o) acc[o] = 0.f;

    for (int cin = 0; cin < CIN; ++cin) {
        const float* fp = feat + (size_t)cin * PLANE;
        for (int i = threadIdx.x; i < 340; i += 256) {
            int hr = i / 34, hc = i % 34;
            int col = x0 + hc; col = min(col, PADW-1);
            tile[hr][hc] = fp[(size_t)(y0 + hr)*PADW + col];
        }
        __syncthreads();

        float in9[9];
        #pragma unroll
        for (int ky = 0; ky < 3; ++ky)
            #pragma unroll
            for (int kx = 0; kx < 3; ++kx)
                in9[ky*3+kx] = tile[r+ky][cx+kx];

        const float* wp = w + ((size_t)oc0*CIN + cin)*9;
        #pragma unroll
        for (int o = 0; o < 16; ++o) {
            const float* wo = wp + (size_t)o*CIN*9;
            float s = acc[o];
            #pragma unroll
            for (int k = 0; k < 9; ++k) s += wo[k]*in9[k];
            acc[o] = s;
        }
        __syncthreads();
    }

    int x = x0 + cx, y = y0 + r;
    if (x < BW) {
        #pragma unroll
        for (int o = 0; o < 16; ++o)
            out[(size_t)(oc0 + o)*NPIX + y*BW + x] = acc[o] + bias[oc0 + o];
    }
}

// ---------------------------------------------------------------------------
extern "C" void kernel_launch(void* const* d_in, const int* in_sizes, int n_in,
                              void* d_out, int out_size, void* d_ws, size_t ws_size,
                              hipStream_t stream)
{
    const float* cam_feat = (const float*)d_in[0];   // [6][128][64][176]
    const float* ego2cam  = (const float*)d_in[1];   // [1][6][4][4]
    const float* conv_w   = (const float*)d_in[2];   // [128][655][3][3]
    const float* conv_b   = (const float*)d_in[3];   // [128]
    const int*   img_h    = (const int*)d_in[4];
    const int*   img_w    = (const int*)d_in[5];
    float* out = (float*)d_out;

    // workspace layout (f32): camt 8,650,752 | feat 655*29524 = 19,338,220
    float* camt = (float*)d_ws;
    float* feat = camt + (size_t)NCAM*CH*FH*FW;

    transpose_kernel<<<dim3(6, FH, NCAM), 256, 0, stream>>>(cam_feat, camt);
    border_kernel<<<CIN, 256, 0, stream>>>(feat);
    proj_kernel<<<NPIX, 128, 0, stream>>>(camt, ego2cam, img_h, img_w, feat);
    conv_kernel<<<dim3(8, 15, 8), 256, 0, stream>>>(feat, conv_w, conv_b, out);
}

// Round 2
// 193.643 us; speedup vs baseline: 7.6544x; 7.6544x over previous
//
#include <hip/hip_runtime.h>
#include <hip/hip_bf16.h>

#define BH 120
#define BW 240
#define NLVL 5
#define NCAM 6
#define CH 128
#define FH 64
#define FW 176
#define CIN 655
#define CINP 672            // padded to 21*32
#define NCT 21
#define FROWS 124           // padded rows 0..121 used, 122..123 safety
#define FCOLS 242
#define NPIX (BH*BW)

typedef __hip_bfloat16 bf16;
typedef __attribute__((ext_vector_type(8))) short s16x8;
typedef __attribute__((ext_vector_type(4))) float f32x4;

#define G_AS __attribute__((address_space(1)))
#define L_AS __attribute__((address_space(3)))

// ---------------------------------------------------------------------------
// Kernel T: transpose cam_feat [6][128][64][176] f32 -> camt [6][64][176][128]
// ---------------------------------------------------------------------------
__global__ __launch_bounds__(256) void transpose_kernel(
    const float* __restrict__ in, float* __restrict__ out)
{
    __shared__ float t[32][129];
    int n = blockIdx.z, h = blockIdx.y, w0 = blockIdx.x * 32;
    int wlim = min(32, FW - w0);
    int wx = threadIdx.x & 31, cg = threadIdx.x >> 5;
    if (wx < wlim) {
        #pragma unroll
        for (int k = 0; k < 16; ++k) {
            int c = cg + k * 8;
            t[wx][c] = in[((n*CH + c)*FH + h)*FW + w0 + wx];
        }
    }
    __syncthreads();
    int c2 = threadIdx.x & 127, wi = threadIdx.x >> 7;
    for (int w = wi; w < wlim; w += 2)
        out[((n*FH + h)*FW + w0 + w)*CH + c2] = t[w][c2];
}

// ---------------------------------------------------------------------------
// Kernel W: conv_w [128][655][3][3] f32 -> wbf [9][128][672] bf16 (tail zero)
// ---------------------------------------------------------------------------
__global__ __launch_bounds__(256) void wprep_kernel(
    const float* __restrict__ w, bf16* __restrict__ wbf)
{
    int idx = blockIdx.x * 256 + threadIdx.x;      // (oc, cin)
    if (idx >= 128 * CINP) return;
    int oc = idx / CINP, cin = idx - oc * CINP;
    float v[9];
    if (cin < CIN) {
        const float* s = w + ((size_t)oc * CIN + cin) * 9;
        #pragma unroll
        for (int k = 0; k < 9; ++k) v[k] = s[k];
    } else {
        #pragma unroll
        for (int k = 0; k < 9; ++k) v[k] = 0.f;
    }
    #pragma unroll
    for (int k = 0; k < 9; ++k)
        wbf[(size_t)(k * 128 + oc) * CINP + cin] = __float2bfloat16(v[k]);
}

// ---------------------------------------------------------------------------
// Kernel P: per BEV pixel, project/sample/average, write NHWC bf16 feat
// feat[pady][padx][cin], cin = ch*5+lvl (ch 0..130). Borders stay memset-0.
// ---------------------------------------------------------------------------
__global__ __launch_bounds__(128) void proj_kernel(
    const float* __restrict__ camt,
    const float* __restrict__ e2c,
    const int* __restrict__ pimgh, const int* __restrict__ pimgw,
    bf16* __restrict__ feat)
{
    __shared__ float sfx[30], sfy[30];
    __shared__ int   six[30], siy[30], svalid[30];

    int pix = blockIdx.x;
    int bx = pix % BW, by = pix / BW;
    float xw = (float)(-30.0 + bx * (60.0/239.0)); if (bx == BW-1) xw = 30.f;
    float yw = (float)(-15.0 + by * (30.0/119.0)); if (by == BH-1) yw = 15.f;

    int t = threadIdx.x;
    if (t < 30) {
        int l = t / 6, cam = t % 6;
        float h = -1.f + 0.5f * (float)l;
        const float* M = e2c + cam * 16;
        float cx = M[0]*xw + M[1]*yw + M[2]*h  + M[3];
        float cy = M[4]*xw + M[5]*yw + M[6]*h  + M[7];
        float cz = M[8]*xw + M[9]*yw + M[10]*h + M[11];
        float fw = (float)pimgw[0], fh = (float)pimgh[0];
        float px = ((cx/cz + 1e-9f)/fw - 0.5f) * 2.f;
        float py = ((cy/cz + 1e-9f)/fh - 0.5f) * 2.f;
        bool valid = (cz > 1e-9f) && (px > -1.f) && (px < 1.f)
                                  && (py > -1.f) && (py < 1.f);
        float xs = ((px + 1.f)*(float)FW - 1.f) * 0.5f;
        float ys = ((py + 1.f)*(float)FH - 1.f) * 0.5f;
        float x0 = floorf(xs), y0 = floorf(ys);
        sfx[t] = xs - x0;  sfy[t] = ys - y0;
        six[t] = (int)x0;  siy[t] = (int)y0;
        svalid[t] = valid ? 1 : 0;
    }
    __syncthreads();

    int c = t;
    float vals[NLVL];
    #pragma unroll
    for (int l = 0; l < NLVL; ++l) {
        float acc = 0.f; int cnt = 0;
        #pragma unroll
        for (int cam = 0; cam < NCAM; ++cam) {
            int id = l*6 + cam;
            if (svalid[id]) {
                int ix = six[id], iy = siy[id];
                float fx = sfx[id], fy = sfy[id];
                const float* bp = camt + (((size_t)cam*FH + iy)*FW + ix)*CH + c;
                float v00 = (ix >= 0    && iy >= 0   ) ? bp[0]        : 0.f;
                float v01 = (ix >= 0    && iy <  FH-1) ? bp[FW*CH]    : 0.f;
                float v10 = (ix <  FW-1 && iy >= 0   ) ? bp[CH]       : 0.f;
                float v11 = (ix <  FW-1 && iy <  FH-1) ? bp[FW*CH+CH] : 0.f;
                acc += (1.f-fx)*(1.f-fy)*v00 + (1.f-fx)*fy*v01
                     +      fx *(1.f-fy)*v10 +      fx *fy*v11;
                cnt++;
            }
        }
        vals[l] = acc / (float)(cnt > 0 ? cnt : 1);
    }

    bf16* dst = feat + ((size_t)(by+1)*FCOLS + (bx+1))*CINP;
    #pragma unroll
    for (int l = 0; l < NLVL; ++l)
        dst[c*5 + l] = __float2bfloat16(vals[l]);
    if (t < 15) {
        int j = t / 5, l = t % 5;
        float v = (j == 0) ? xw : (j == 1) ? yw : (-1.f + 0.5f*(float)l);
        dst[(CH + j)*5 + l] = __float2bfloat16(v);
    }
}

// ---------------------------------------------------------------------------
// Kernel C: implicit-GEMM 3x3 conv via MFMA 16x16x32 bf16.
// Block: 128 oc x (8 rows x 16 cols) px. 4 waves; wave = 128 oc x 2 row-frags.
// K-loop: 21 cin-tiles x 9 offsets. LDS double-buffered halo (192px x 64B)
// + weights (128oc x 64B), staged with global_load_lds; XOR chunk-swizzle
// applied on source address + read address (linear LDS dest, rule #21).
// ---------------------------------------------------------------------------
__global__ __launch_bounds__(256, 1) void conv_mfma_kernel(
    const bf16* __restrict__ feat,     // [124][242][672]
    const bf16* __restrict__ wbf,      // [9][128][672]
    const float* __restrict__ bias,
    float* __restrict__ out)           // [128][120][240]
{
    __shared__ __align__(16) char lds[40960];
    const int tid  = threadIdx.x;
    const int wv   = tid >> 6;
    const int lane = tid & 63;
    const int t15  = tid & 15;
    const int kgl  = (tid >> 4) & 3;
    const int y0p = blockIdx.y * 8;        // padded row base
    const int x0p = blockIdx.x * 16;       // padded col base

    const int HB0 = 0, HB1 = 12288, WB0 = 24576, WB1 = 32768;

    f32x4 acc[8][2];
    #pragma unroll
    for (int m = 0; m < 8; ++m)
        #pragma unroll
        for (int f = 0; f < 2; ++f)
            acc[m][f] = (f32x4){0.f, 0.f, 0.f, 0.f};

    auto stageW = [&](int ct, int off, int wb) {
        #pragma unroll
        for (int jj = 0; jj < 2; ++jj) {
            int j = 2*wv + jj;                    // 8 wave-issues total
            int cch = j*64 + lane;
            int oc = cch >> 2, kgp = cch & 3;
            int kg = kgp ^ ((oc >> 1) & 3);       // source carries the swizzle
            const bf16* src = wbf + ((size_t)(off*128 + oc)*CINP + ct*32 + kg*8);
            __builtin_amdgcn_global_load_lds((const G_AS void*)src,
                                             (L_AS void*)(lds + wb + j*1024),
                                             16, 0, 0);
        }
    };
    auto stageH = [&](int ct, int hb) {
        #pragma unroll
        for (int kk = 0; kk < 3; ++kk) {
            int j = wv + 4*kk;                    // 12 wave-issues total
            int cch = j*64 + lane;
            int pp = cch >> 2, kgp = cch & 3;     // pp: halo pixel 0..191
            int kg = kgp ^ ((pp >> 1) & 3);
            int row = pp / 18;
            int col = pp - row*18;
            const bf16* src = feat + ((size_t)(y0p + row)*FCOLS + (x0p + col))*CINP
                                   + ct*32 + kg*8;
            __builtin_amdgcn_global_load_lds((const G_AS void*)src,
                                             (L_AS void*)(lds + hb + j*1024),
                                             16, 0, 0);
        }
    };

    stageH(0, HB0);
    stageW(0, 0, WB0);
    __syncthreads();

    int ct = 0, off = 0;
    for (int p = 0; p < 189; ++p) {
        if (p < 188) {                             // prefetch next tile
            int off1 = off + 1, ct1 = ct;
            if (off1 == 9) { off1 = 0; ++ct1; }
            stageW(ct1, off1, ((p+1) & 1) ? WB1 : WB0);
            if (off1 == 0) stageH(ct1, (ct1 & 1) ? HB1 : HB0);
        }
        const int wb = (p & 1) ? WB1 : WB0;
        const int hb = (ct & 1) ? HB1 : HB0;
        const int ky = off / 3, kx = off - ky*3;

        s16x8 A[8];
        #pragma unroll
        for (int m = 0; m < 8; ++m) {
            int oc = m*16 + t15;
            A[m] = *(const s16x8*)(lds + wb + oc*64 + ((kgl ^ ((oc>>1)&3)) << 4));
        }
        #pragma unroll
        for (int f = 0; f < 2; ++f) {
            int prow = (2*wv + f + ky)*18 + t15 + kx;
            s16x8 Bv = *(const s16x8*)(lds + hb + prow*64 + ((kgl ^ ((prow>>1)&3)) << 4));
            #pragma unroll
            for (int m = 0; m < 8; ++m)
                acc[m][f] = __builtin_amdgcn_mfma_f32_16x16x32_bf16(A[m], Bv, acc[m][f], 0, 0, 0);
        }
        __syncthreads();
        if (++off == 9) { off = 0; ++ct; }
    }

    const int xo = x0p + t15;
    #pragma unroll
    for (int m = 0; m < 8; ++m) {
        #pragma unroll
        for (int r = 0; r < 4; ++r) {
            int oc = m*16 + kgl*4 + r;             // D: row=(lane>>4)*4+r
            float b = bias[oc];
            #pragma unroll
            for (int f = 0; f < 2; ++f) {
                int y = y0p + 2*wv + f;
                out[(size_t)oc*NPIX + y*BW + xo] = acc[m][f][r] + b;
            }
        }
    }
}

// ---------------------------------------------------------------------------
extern "C" void kernel_launch(void* const* d_in, const int* in_sizes, int n_in,
                              void* d_out, int out_size, void* d_ws, size_t ws_size,
                              hipStream_t stream)
{
    const float* cam_feat = (const float*)d_in[0];
    const float* ego2cam  = (const float*)d_in[1];
    const float* conv_w   = (const float*)d_in[2];
    const float* conv_b   = (const float*)d_in[3];
    const int*   img_h    = (const int*)d_in[4];
    const int*   img_w    = (const int*)d_in[5];
    float* out = (float*)d_out;

    // ws layout: camt f32 [6*64*176*128] | feat bf16 [124*242*672] | wbf bf16 [9*128*672]
    float* camt = (float*)d_ws;
    bf16* feat = (bf16*)(camt + (size_t)NCAM*CH*FH*FW);
    bf16* wbf  = feat + (size_t)FROWS*FCOLS*CINP;

    hipMemsetAsync(feat, 0, (size_t)FROWS*FCOLS*CINP*sizeof(bf16), stream);
    transpose_kernel<<<dim3(6, FH, NCAM), 256, 0, stream>>>(cam_feat, camt);
    wprep_kernel<<<(128*CINP + 255)/256, 256, 0, stream>>>(conv_w, wbf);
    proj_kernel<<<NPIX, 128, 0, stream>>>(camt, ego2cam, img_h, img_w, feat);
    conv_mfma_kernel<<<dim3(15, 15), 256, 0, stream>>>(feat, wbf, conv_b, out);
}

// Round 3
// 123.468 us; speedup vs baseline: 12.0048x; 1.5684x over previous
//
#include <hip/hip_runtime.h>
#include <hip/hip_bf16.h>

#define BH 120
#define BW 240
#define NLVL 5
#define NCAM 6
#define CH 128
#define FH 64
#define FW 176
#define CIN 655
#define CINP 672            // padded to 21*32
#define NCT 21
#define FROWS 124           // padded rows; 0..121 used, 122..123 slack
#define FCOLS 242
#define NPIX (BH*BW)

typedef __hip_bfloat16 bf16;
typedef __attribute__((ext_vector_type(8))) short s16x8;
typedef __attribute__((ext_vector_type(4))) float f32x4;

#define G_AS __attribute__((address_space(1)))
#define L_AS __attribute__((address_space(3)))

__device__ __forceinline__ float bf2f(unsigned short u) {
    union { unsigned int i; float f; } c; c.i = ((unsigned int)u) << 16; return c.f;
}

// ---------------------------------------------------------------------------
// Kernel T: transpose cam_feat [6][128][64][176] f32 -> camt [6][64][176][128]
// ---------------------------------------------------------------------------
__global__ __launch_bounds__(256) void transpose_kernel(
    const float* __restrict__ in, float* __restrict__ out)
{
    __shared__ float t[32][129];
    int n = blockIdx.z, h = blockIdx.y, w0 = blockIdx.x * 32;
    int wlim = min(32, FW - w0);
    int wx = threadIdx.x & 31, cg = threadIdx.x >> 5;
    if (wx < wlim) {
        #pragma unroll
        for (int k = 0; k < 16; ++k) {
            int c = cg + k * 8;
            t[wx][c] = in[((n*CH + c)*FH + h)*FW + w0 + wx];
        }
    }
    __syncthreads();
    int c2 = threadIdx.x & 127, wi = threadIdx.x >> 7;
    for (int w = wi; w < wlim; w += 2)
        out[((n*FH + h)*FW + w0 + w)*CH + c2] = t[w][c2];
}

// ---------------------------------------------------------------------------
// Kernel W: conv_w [128][655][3][3] f32 -> wbf [9][128][672] bf16 (tail zero)
// ---------------------------------------------------------------------------
__global__ __launch_bounds__(256) void wprep_kernel(
    const float* __restrict__ w, bf16* __restrict__ wbf)
{
    int idx = blockIdx.x * 256 + threadIdx.x;
    if (idx >= 128 * CINP) return;
    int oc = idx / CINP, cin = idx - oc * CINP;
    float v[9];
    if (cin < CIN) {
        const float* s = w + ((size_t)oc * CIN + cin) * 9;
        #pragma unroll
        for (int k = 0; k < 9; ++k) v[k] = s[k];
    } else {
        #pragma unroll
        for (int k = 0; k < 9; ++k) v[k] = 0.f;
    }
    #pragma unroll
    for (int k = 0; k < 9; ++k)
        wbf[(size_t)(k * 128 + oc) * CINP + cin] = __float2bfloat16(v[k]);
}

// ---------------------------------------------------------------------------
// Kernel Z: zero the 724 border pixels (rows 0,121; cols 0,241) across all
// 672 cin. Interior is fully written by proj; cin tail 655..671 anywhere is
// garbage x zero-weights = 0, so no full memset needed.
// ---------------------------------------------------------------------------
__global__ __launch_bounds__(128) void border_kernel(bf16* __restrict__ feat)
{
    int b = blockIdx.x;            // 0..723
    int row, col;
    if (b < 242)      { row = 0;   col = b; }
    else if (b < 484) { row = 121; col = b - 242; }
    else if (b < 604) { row = b - 484 + 1; col = 0; }
    else              { row = b - 604 + 1; col = 241; }
    s16x8* p = (s16x8*)(feat + ((size_t)row*FCOLS + col)*CINP);
    int t = threadIdx.x;
    if (t < 84) p[t] = (s16x8){0,0,0,0,0,0,0,0};
}

// ---------------------------------------------------------------------------
// Kernel P: per BEV pixel, project/sample/average, write NHWC bf16 feat
// ---------------------------------------------------------------------------
__global__ __launch_bounds__(128) void proj_kernel(
    const float* __restrict__ camt,
    const float* __restrict__ e2c,
    const int* __restrict__ pimgh, const int* __restrict__ pimgw,
    bf16* __restrict__ feat)
{
    __shared__ float sfx[30], sfy[30];
    __shared__ int   six[30], siy[30], svalid[30];

    int pix = blockIdx.x;
    int bx = pix % BW, by = pix / BW;
    float xw = (float)(-30.0 + bx * (60.0/239.0)); if (bx == BW-1) xw = 30.f;
    float yw = (float)(-15.0 + by * (30.0/119.0)); if (by == BH-1) yw = 15.f;

    int t = threadIdx.x;
    if (t < 30) {
        int l = t / 6, cam = t % 6;
        float h = -1.f + 0.5f * (float)l;
        const float* M = e2c + cam * 16;
        float cx = M[0]*xw + M[1]*yw + M[2]*h  + M[3];
        float cy = M[4]*xw + M[5]*yw + M[6]*h  + M[7];
        float cz = M[8]*xw + M[9]*yw + M[10]*h + M[11];
        float fw = (float)pimgw[0], fh = (float)pimgh[0];
        float px = ((cx/cz + 1e-9f)/fw - 0.5f) * 2.f;
        float py = ((cy/cz + 1e-9f)/fh - 0.5f) * 2.f;
        bool valid = (cz > 1e-9f) && (px > -1.f) && (px < 1.f)
                                  && (py > -1.f) && (py < 1.f);
        float xs = ((px + 1.f)*(float)FW - 1.f) * 0.5f;
        float ys = ((py + 1.f)*(float)FH - 1.f) * 0.5f;
        float x0 = floorf(xs), y0 = floorf(ys);
        sfx[t] = xs - x0;  sfy[t] = ys - y0;
        six[t] = (int)x0;  siy[t] = (int)y0;
        svalid[t] = valid ? 1 : 0;
    }
    __syncthreads();

    int c = t;
    float vals[NLVL];
    #pragma unroll
    for (int l = 0; l < NLVL; ++l) {
        float acc = 0.f; int cnt = 0;
        #pragma unroll
        for (int cam = 0; cam < NCAM; ++cam) {
            int id = l*6 + cam;
            if (svalid[id]) {
                int ix = six[id], iy = siy[id];
                float fx = sfx[id], fy = sfy[id];
                const float* bp = camt + (((size_t)cam*FH + iy)*FW + ix)*CH + c;
                float v00 = (ix >= 0    && iy >= 0   ) ? bp[0]        : 0.f;
                float v01 = (ix >= 0    && iy <  FH-1) ? bp[FW*CH]    : 0.f;
                float v10 = (ix <  FW-1 && iy >= 0   ) ? bp[CH]       : 0.f;
                float v11 = (ix <  FW-1 && iy <  FH-1) ? bp[FW*CH+CH] : 0.f;
                acc += (1.f-fx)*(1.f-fy)*v00 + (1.f-fx)*fy*v01
                     +      fx *(1.f-fy)*v10 +      fx *fy*v11;
                cnt++;
            }
        }
        vals[l] = acc / (float)(cnt > 0 ? cnt : 1);
    }

    bf16* dst = feat + ((size_t)(by+1)*FCOLS + (bx+1))*CINP;
    #pragma unroll
    for (int l = 0; l < NLVL; ++l)
        dst[c*5 + l] = __float2bfloat16(vals[l]);
    if (t < 15) {
        int j = t / 5, l = t % 5;
        float v = (j == 0) ? xw : (j == 1) ? yw : (-1.f + 0.5f*(float)l);
        dst[(CH + j)*5 + l] = __float2bfloat16(v);
    }
}

// ---------------------------------------------------------------------------
// Kernel C: implicit-GEMM 3x3 conv via MFMA 16x16x32 bf16, K-split x4.
// Grid (15,15,4): block = 128 oc x (8 rows x 16 cols) px, quarter q of the
// 21 cin-tiles. Writes bf16 partial sums part[q][oc][pix]. 40KB LDS x 4
// blocks/CU = 160KB -> ~3.5 blocks/CU co-resident to hide phase drains.
// ---------------------------------------------------------------------------
__global__ __launch_bounds__(256, 4) void conv_mfma_kernel(
    const bf16* __restrict__ feat,     // [124][242][672]
    const bf16* __restrict__ wbf,      // [9][128][672]
    bf16* __restrict__ part)           // [4][128][28800]
{
    __shared__ __align__(16) char lds[40960];
    const int tid  = threadIdx.x;
    const int wv   = tid >> 6;
    const int lane = tid & 63;
    const int t15  = tid & 15;
    const int kgl  = (tid >> 4) & 3;
    const int y0p = blockIdx.y * 8;
    const int x0p = blockIdx.x * 16;
    const int q   = blockIdx.z;
    const int ct0 = q ? (1 + 5*q) : 0;         // 0,6,11,16
    const int nph = (q ? 5 : 6) * 9;

    const int HB0 = 0, HB1 = 12288, WB0 = 24576, WB1 = 32768;

    f32x4 acc[8][2];
    #pragma unroll
    for (int m = 0; m < 8; ++m)
        #pragma unroll
        for (int f = 0; f < 2; ++f)
            acc[m][f] = (f32x4){0.f, 0.f, 0.f, 0.f};

    auto stageW = [&](int ct, int off, int wb) {
        #pragma unroll
        for (int jj = 0; jj < 2; ++jj) {
            int j = 2*wv + jj;
            int cch = j*64 + lane;
            int oc = cch >> 2, kgp = cch & 3;
            int kg = kgp ^ ((oc >> 1) & 3);
            const bf16* src = wbf + ((size_t)(off*128 + oc)*CINP + ct*32 + kg*8);
            __builtin_amdgcn_global_load_lds((const G_AS void*)src,
                                             (L_AS void*)(lds + wb + j*1024),
                                             16, 0, 0);
        }
    };
    auto stageH = [&](int ct, int hb) {
        #pragma unroll
        for (int kk = 0; kk < 3; ++kk) {
            int j = wv + 4*kk;
            int cch = j*64 + lane;
            int pp = cch >> 2, kgp = cch & 3;
            int kg = kgp ^ ((pp >> 1) & 3);
            int row = pp / 18;
            int col = pp - row*18;
            const bf16* src = feat + ((size_t)(y0p + row)*FCOLS + (x0p + col))*CINP
                                   + ct*32 + kg*8;
            __builtin_amdgcn_global_load_lds((const G_AS void*)src,
                                             (L_AS void*)(lds + hb + j*1024),
                                             16, 0, 0);
        }
    };

    stageH(ct0, HB0);
    stageW(ct0, 0, WB0);
    __syncthreads();

    int lct = 0, off = 0;
    for (int p = 0; p < nph; ++p) {
        if (p + 1 < nph) {
            int off1 = off + 1, lct1 = lct;
            if (off1 == 9) { off1 = 0; ++lct1; }
            stageW(ct0 + lct1, off1, ((p+1) & 1) ? WB1 : WB0);
            if (off1 == 0) stageH(ct0 + lct1, (lct1 & 1) ? HB1 : HB0);
        }
        const int wb = (p & 1) ? WB1 : WB0;
        const int hb = (lct & 1) ? HB1 : HB0;
        const int ky = off / 3, kx = off - ky*3;

        s16x8 A[8];
        #pragma unroll
        for (int m = 0; m < 8; ++m) {
            int oc = m*16 + t15;
            A[m] = *(const s16x8*)(lds + wb + oc*64 + ((kgl ^ ((oc>>1)&3)) << 4));
        }
        #pragma unroll
        for (int f = 0; f < 2; ++f) {
            int prow = (2*wv + f + ky)*18 + t15 + kx;
            s16x8 Bv = *(const s16x8*)(lds + hb + prow*64 + ((kgl ^ ((prow>>1)&3)) << 4));
            __builtin_amdgcn_s_setprio(1);
            #pragma unroll
            for (int m = 0; m < 8; ++m)
                acc[m][f] = __builtin_amdgcn_mfma_f32_16x16x32_bf16(A[m], Bv, acc[m][f], 0, 0, 0);
            __builtin_amdgcn_s_setprio(0);
        }
        __syncthreads();
        if (++off == 9) { off = 0; ++lct; }
    }

    bf16* pq = part + (size_t)q * (128*NPIX);
    const int xo = x0p + t15;
    #pragma unroll
    for (int m = 0; m < 8; ++m) {
        #pragma unroll
        for (int r = 0; r < 4; ++r) {
            int oc = m*16 + kgl*4 + r;
            #pragma unroll
            for (int f = 0; f < 2; ++f) {
                int y = y0p + 2*wv + f;
                pq[(size_t)oc*NPIX + y*BW + xo] = __float2bfloat16(acc[m][f][r]);
            }
        }
    }
}

// ---------------------------------------------------------------------------
// Kernel R: out[oc][pix] = sum_q part[q][oc][pix] + bias[oc]
// ---------------------------------------------------------------------------
__global__ __launch_bounds__(256) void combine_kernel(
    const bf16* __restrict__ part, const float* __restrict__ bias,
    float* __restrict__ out)
{
    int i8 = blockIdx.x * 256 + threadIdx.x;     // 8-element group
    if (i8 >= 128*NPIX/8) return;
    int oc = i8 / (NPIX/8);
    float s[8];
    float b = bias[oc];
    #pragma unroll
    for (int k = 0; k < 8; ++k) s[k] = b;
    #pragma unroll
    for (int qq = 0; qq < 4; ++qq) {
        s16x8 v = *(const s16x8*)(part + (size_t)qq*(128*NPIX) + (size_t)i8*8);
        #pragma unroll
        for (int k = 0; k < 8; ++k) s[k] += bf2f((unsigned short)v[k]);
    }
    f32x4* o = (f32x4*)(out + (size_t)i8*8);
    o[0] = (f32x4){s[0], s[1], s[2], s[3]};
    o[1] = (f32x4){s[4], s[5], s[6], s[7]};
}

// ---------------------------------------------------------------------------
extern "C" void kernel_launch(void* const* d_in, const int* in_sizes, int n_in,
                              void* d_out, int out_size, void* d_ws, size_t ws_size,
                              hipStream_t stream)
{
    const float* cam_feat = (const float*)d_in[0];
    const float* ego2cam  = (const float*)d_in[1];
    const float* conv_w   = (const float*)d_in[2];
    const float* conv_b   = (const float*)d_in[3];
    const int*   img_h    = (const int*)d_in[4];
    const int*   img_w    = (const int*)d_in[5];
    float* out = (float*)d_out;

    // ws: camt f32 [6*64*176*128]=34.6MB | feat bf16 [124*242*672]=40.3MB |
    //     wbf bf16 [9*128*672]. Partials (bf16, 29.5MB) ALIAS camt (dead
    //     after proj; rewritten by transpose every call).
    float* camt = (float*)d_ws;
    bf16* feat = (bf16*)(camt + (size_t)NCAM*CH*FH*FW);
    bf16* wbf  = feat + (size_t)FROWS*FCOLS*CINP;
    bf16* part = (bf16*)d_ws;

    transpose_kernel<<<dim3(6, FH, NCAM), 256, 0, stream>>>(cam_feat, camt);
    wprep_kernel<<<(128*CINP + 255)/256, 256, 0, stream>>>(conv_w, wbf);
    border_kernel<<<724, 128, 0, stream>>>(feat);
    proj_kernel<<<NPIX, 128, 0, stream>>>(camt, ego2cam, img_h, img_w, feat);
    conv_mfma_kernel<<<dim3(15, 15, 4), 256, 0, stream>>>(feat, wbf, part);
    combine_kernel<<<(128*NPIX/8 + 255)/256, 256, 0, stream>>>(part, conv_b, out);
}

// Round 5
// 118.777 us; speedup vs baseline: 12.4790x; 1.0395x over previous
//
#include <hip/hip_runtime.h>
#include <hip/hip_bf16.h>

#define BH 120
#define BW 240
#define NLVL 5
#define NCAM 6
#define CH 128
#define FH 64
#define FW 176
#define CIN 655
#define CINP 672            // padded to 21*32
#define NCT 21
#define FROWS 124           // padded rows; 0..121 used, 122..123 slack
#define FCOLS 242
#define NPIX (BH*BW)

typedef __hip_bfloat16 bf16;
typedef __attribute__((ext_vector_type(8))) short s16x8;
typedef __attribute__((ext_vector_type(4))) float f32x4;
typedef __attribute__((ext_vector_type(2))) float f32x2;
typedef unsigned int uint;
typedef __attribute__((ext_vector_type(4), aligned(4))) uint uint4a;

#define G_AS __attribute__((address_space(1)))
#define L_AS __attribute__((address_space(3)))

__device__ __forceinline__ float bf2f(unsigned short u) {
    union { unsigned int i; float f; } c; c.i = ((unsigned int)u) << 16; return c.f;
}
__device__ __forceinline__ uint f2bu(float x) {
    return (uint)__hip_bfloat16_raw(__float2bfloat16(x)).x;
}

// ---------------------------------------------------------------------------
// Kernel T: transpose cam_feat [6][128][64][176] f32 -> camt [6][64][176][128]
// ---------------------------------------------------------------------------
__global__ __launch_bounds__(256) void transpose_kernel(
    const float* __restrict__ in, float* __restrict__ out)
{
    __shared__ float t[32][129];
    int n = blockIdx.z, h = blockIdx.y, w0 = blockIdx.x * 32;
    int wlim = min(32, FW - w0);
    int wx = threadIdx.x & 31, cg = threadIdx.x >> 5;
    if (wx < wlim) {
        #pragma unroll
        for (int k = 0; k < 16; ++k) {
            int c = cg + k * 8;
            t[wx][c] = in[((n*CH + c)*FH + h)*FW + w0 + wx];
        }
    }
    __syncthreads();
    int c2 = threadIdx.x & 127, wi = threadIdx.x >> 7;
    for (int w = wi; w < wlim; w += 2)
        out[((n*FH + h)*FW + w0 + w)*CH + c2] = t[w][c2];
}

// ---------------------------------------------------------------------------
// Kernel W: conv_w [128][655][3][3] f32 -> wbf [9][128][672] bf16 (tail zero)
// ---------------------------------------------------------------------------
__global__ __launch_bounds__(256) void wprep_kernel(
    const float* __restrict__ w, bf16* __restrict__ wbf)
{
    int idx = blockIdx.x * 256 + threadIdx.x;
    if (idx >= 128 * CINP) return;
    int oc = idx / CINP, cin = idx - oc * CINP;
    float v[9];
    if (cin < CIN) {
        const float* s = w + ((size_t)oc * CIN + cin) * 9;
        #pragma unroll
        for (int k = 0; k < 9; ++k) v[k] = s[k];
    } else {
        #pragma unroll
        for (int k = 0; k < 9; ++k) v[k] = 0.f;
    }
    #pragma unroll
    for (int k = 0; k < 9; ++k)
        wbf[(size_t)(k * 128 + oc) * CINP + cin] = __float2bfloat16(v[k]);
}

// ---------------------------------------------------------------------------
// Kernel Z: zero the 724 border pixels across all 672 cin.
// ---------------------------------------------------------------------------
__global__ __launch_bounds__(128) void border_kernel(bf16* __restrict__ feat)
{
    int b = blockIdx.x;            // 0..723
    int row, col;
    if (b < 242)      { row = 0;   col = b; }
    else if (b < 484) { row = 121; col = b - 242; }
    else if (b < 604) { row = b - 484 + 1; col = 0; }
    else              { row = b - 604 + 1; col = 241; }
    s16x8* p = (s16x8*)(feat + ((size_t)row*FCOLS + col)*CINP);
    int t = threadIdx.x;
    if (t < 84) p[t] = (s16x8){0,0,0,0,0,0,0,0};
}

// ---------------------------------------------------------------------------
// Kernel P v2: 1 wave = 1 BEV pixel (block 256 = 4 px). Lanes<30 precompute
// per-(l,cam): tap base offset (clamped in-bounds, -1 if invalid) and 4
// bilinear weights with boundary masks AND 1/cnt folded in. Main loop:
// thread = 2 channels, float2 taps, 8 FMA per valid (l,cam).
// ---------------------------------------------------------------------------
__global__ __launch_bounds__(256) void proj_kernel(
    const float* __restrict__ camt,
    const float* __restrict__ e2c,
    const int* __restrict__ pimgh, const int* __restrict__ pimgw,
    bf16* __restrict__ feat)
{
    __shared__ int   s_soff[4][32];
    __shared__ float s_w4[4][30][4];
    __shared__ int   s_val[4][32];

    const int wv = threadIdx.x >> 6;
    const int lane = threadIdx.x & 63;
    const int pix = blockIdx.x * 4 + wv;
    const int bx = pix % BW, by = pix / BW;
    float xw = (float)(-30.0 + bx * (60.0/239.0)); if (bx == BW-1) xw = 30.f;
    float yw = (float)(-15.0 + by * (30.0/119.0)); if (by == BH-1) yw = 15.f;

    const bool act = lane < 30;
    int valid = 0, ix = 0, iy = 0, cam = 0;
    float fx = 0.f, fy = 0.f;
    if (act) {
        int l = lane / 6; cam = lane - l*6;
        float h = -1.f + 0.5f * (float)l;
        const float* M = e2c + cam * 16;
        float cx = M[0]*xw + M[1]*yw + M[2]*h  + M[3];
        float cy = M[4]*xw + M[5]*yw + M[6]*h  + M[7];
        float cz = M[8]*xw + M[9]*yw + M[10]*h + M[11];
        float iw = (float)pimgw[0], ih = (float)pimgh[0];
        float px = ((cx/cz + 1e-9f)/iw - 0.5f) * 2.f;
        float py = ((cy/cz + 1e-9f)/ih - 0.5f) * 2.f;
        valid = (cz > 1e-9f) && (px > -1.f) && (px < 1.f)
                             && (py > -1.f) && (py < 1.f);
        float xs = ((px + 1.f)*(float)FW - 1.f) * 0.5f;
        float ys = ((py + 1.f)*(float)FH - 1.f) * 0.5f;
        float x0 = floorf(xs), y0 = floorf(ys);
        fx = xs - x0; fy = ys - y0;
        ix = (int)x0; iy = (int)y0;
        s_val[wv][lane] = valid;
    }
    __syncthreads();
    if (act) {
        int lbase = (lane / 6) * 6;
        int cnt = s_val[wv][lbase] + s_val[wv][lbase+1] + s_val[wv][lbase+2]
                + s_val[wv][lbase+3] + s_val[wv][lbase+4] + s_val[wv][lbase+5];
        float inv = (cnt > 0) ? (1.f / (float)cnt) : 0.f;
        float sc = valid ? inv : 0.f;
        // boundary-folded weights on clamped base (bx0,by0); sc folded into
        // BOTH x-weights (round-4 bug: gx1 was missing *sc)
        int bx0 = min(max(ix, 0), FW-2);
        int by0 = min(max(iy, 0), FH-2);
        float gx0 = (1.f - fx) * sc, gx1 = fx * sc;
        float wx0 = 0.f, wx1 = 0.f;
        if (ix >= 0)     { if (ix == bx0) wx0 += gx0; else wx1 += gx0; }
        if (ix+1 <= FW-1){ if (ix+1 == bx0) wx0 += gx1; else wx1 += gx1; }
        float wy0 = 0.f, wy1 = 0.f;
        float gy0 = 1.f - fy, gy1 = fy;
        if (iy >= 0)     { if (iy == by0) wy0 += gy0; else wy1 += gy0; }
        if (iy+1 <= FH-1){ if (iy+1 == by0) wy0 += gy1; else wy1 += gy1; }
        s_w4[wv][lane][0] = wx0 * wy0;   // tap (bx0,   by0)
        s_w4[wv][lane][1] = wx0 * wy1;   // tap (bx0,   by0+1)
        s_w4[wv][lane][2] = wx1 * wy0;   // tap (bx0+1, by0)
        s_w4[wv][lane][3] = wx1 * wy1;   // tap (bx0+1, by0+1)
        s_soff[wv][lane] = valid ? ((cam*FH + by0)*FW + bx0)*CH : -1;
    }
    __syncthreads();

    const int c2 = lane * 2;
    float va[NLVL], vb[NLVL];
    #pragma unroll
    for (int l = 0; l < NLVL; ++l) { va[l] = 0.f; vb[l] = 0.f; }

    #pragma unroll
    for (int l = 0; l < NLVL; ++l) {
        #pragma unroll
        for (int cm = 0; cm < NCAM; ++cm) {
            int id = l*6 + cm;
            int so = s_soff[wv][id];
            if (so >= 0) {                       // wave-uniform branch
                const float* bp = camt + so + c2;
                f32x2 t0 = *(const f32x2*)(bp);
                f32x2 t2 = *(const f32x2*)(bp + CH);
                f32x2 t1 = *(const f32x2*)(bp + FW*CH);
                f32x2 t3 = *(const f32x2*)(bp + FW*CH + CH);
                float w0 = s_w4[wv][id][0], w1 = s_w4[wv][id][1];
                float w2 = s_w4[wv][id][2], w3 = s_w4[wv][id][3];
                va[l] += w0*t0[0] + w1*t1[0] + w2*t2[0] + w3*t3[0];
                vb[l] += w0*t0[1] + w1*t1[1] + w2*t2[1] + w3*t3[1];
            }
        }
    }

    bf16* dpix = feat + ((size_t)(by+1)*FCOLS + (bx+1))*CINP;
    uint u0 = f2bu(va[0]) | (f2bu(va[1]) << 16);
    uint u1 = f2bu(va[2]) | (f2bu(va[3]) << 16);
    uint u2 = f2bu(va[4]) | (f2bu(vb[0]) << 16);
    uint u3 = f2bu(vb[1]) | (f2bu(vb[2]) << 16);
    uint u4 = f2bu(vb[3]) | (f2bu(vb[4]) << 16);
    char* dst = (char*)(dpix + c2*5);
    *(uint4a*)dst = (uint4a){u0, u1, u2, u3};
    *(uint*)(dst + 16) = u4;
    if (lane < 15) {                 // coord channels 128..130, cin 640+lane
        int j = lane / 5, l = lane - j*5;
        float v = (j == 0) ? xw : (j == 1) ? yw : (-1.f + 0.5f*(float)l);
        dpix[CH*5 + lane] = __float2bfloat16(v);
    }
}

// ---------------------------------------------------------------------------
// Kernel C: implicit-GEMM 3x3 conv via MFMA 16x16x32 bf16, K-split x4.
// ---------------------------------------------------------------------------
__global__ __launch_bounds__(256, 4) void conv_mfma_kernel(
    const bf16* __restrict__ feat,     // [124][242][672]
    const bf16* __restrict__ wbf,      // [9][128][672]
    bf16* __restrict__ part)           // [4][128][28800]
{
    __shared__ __align__(16) char lds[40960];
    const int tid  = threadIdx.x;
    const int wv   = tid >> 6;
    const int lane = tid & 63;
    const int t15  = tid & 15;
    const int kgl  = (tid >> 4) & 3;
    const int y0p = blockIdx.y * 8;
    const int x0p = blockIdx.x * 16;
    const int q   = blockIdx.z;
    const int ct0 = q ? (1 + 5*q) : 0;         // 0,6,11,16
    const int nph = (q ? 5 : 6) * 9;

    const int HB0 = 0, HB1 = 12288, WB0 = 24576, WB1 = 32768;

    f32x4 acc[8][2];
    #pragma unroll
    for (int m = 0; m < 8; ++m)
        #pragma unroll
        for (int f = 0; f < 2; ++f)
            acc[m][f] = (f32x4){0.f, 0.f, 0.f, 0.f};

    auto stageW = [&](int ct, int off, int wb) {
        #pragma unroll
        for (int jj = 0; jj < 2; ++jj) {
            int j = 2*wv + jj;
            int cch = j*64 + lane;
            int oc = cch >> 2, kgp = cch & 3;
            int kg = kgp ^ ((oc >> 1) & 3);
            const bf16* src = wbf + ((size_t)(off*128 + oc)*CINP + ct*32 + kg*8);
            __builtin_amdgcn_global_load_lds((const G_AS void*)src,
                                             (L_AS void*)(lds + wb + j*1024),
                                             16, 0, 0);
        }
    };
    auto stageH = [&](int ct, int hb) {
        #pragma unroll
        for (int kk = 0; kk < 3; ++kk) {
            int j = wv + 4*kk;
            int cch = j*64 + lane;
            int pp = cch >> 2, kgp = cch & 3;
            int kg = kgp ^ ((pp >> 1) & 3);
            int row = pp / 18;
            int col = pp - row*18;
            const bf16* src = feat + ((size_t)(y0p + row)*FCOLS + (x0p + col))*CINP
                                   + ct*32 + kg*8;
            __builtin_amdgcn_global_load_lds((const G_AS void*)src,
                                             (L_AS void*)(lds + hb + j*1024),
                                             16, 0, 0);
        }
    };

    stageH(ct0, HB0);
    stageW(ct0, 0, WB0);
    __syncthreads();

    int lct = 0, off = 0;
    for (int p = 0; p < nph; ++p) {
        if (p + 1 < nph) {
            int off1 = off + 1, lct1 = lct;
            if (off1 == 9) { off1 = 0; ++lct1; }
            stageW(ct0 + lct1, off1, ((p+1) & 1) ? WB1 : WB0);
            if (off1 == 0) stageH(ct0 + lct1, (lct1 & 1) ? HB1 : HB0);
        }
        const int wb = (p & 1) ? WB1 : WB0;
        const int hb = (lct & 1) ? HB1 : HB0;
        const int ky = off / 3, kx = off - ky*3;

        s16x8 A[8];
        #pragma unroll
        for (int m = 0; m < 8; ++m) {
            int oc = m*16 + t15;
            A[m] = *(const s16x8*)(lds + wb + oc*64 + ((kgl ^ ((oc>>1)&3)) << 4));
        }
        #pragma unroll
        for (int f = 0; f < 2; ++f) {
            int prow = (2*wv + f + ky)*18 + t15 + kx;
            s16x8 Bv = *(const s16x8*)(lds + hb + prow*64 + ((kgl ^ ((prow>>1)&3)) << 4));
            __builtin_amdgcn_s_setprio(1);
            #pragma unroll
            for (int m = 0; m < 8; ++m)
                acc[m][f] = __builtin_amdgcn_mfma_f32_16x16x32_bf16(A[m], Bv, acc[m][f], 0, 0, 0);
            __builtin_amdgcn_s_setprio(0);
        }
        __syncthreads();
        if (++off == 9) { off = 0; ++lct; }
    }

    bf16* pq = part + (size_t)q * (128*NPIX);
    const int xo = x0p + t15;
    #pragma unroll
    for (int m = 0; m < 8; ++m) {
        #pragma unroll
        for (int r = 0; r < 4; ++r) {
            int oc = m*16 + kgl*4 + r;
            #pragma unroll
            for (int f = 0; f < 2; ++f) {
                int y = y0p + 2*wv + f;
                pq[(size_t)oc*NPIX + y*BW + xo] = __float2bfloat16(acc[m][f][r]);
            }
        }
    }
}

// ---------------------------------------------------------------------------
// Kernel R: out[oc][pix] = sum_q part[q][oc][pix] + bias[oc]
// ---------------------------------------------------------------------------
__global__ __launch_bounds__(256) void combine_kernel(
    const bf16* __restrict__ part, const float* __restrict__ bias,
    float* __restrict__ out)
{
    int i8 = blockIdx.x * 256 + threadIdx.x;
    if (i8 >= 128*NPIX/8) return;
    int oc = i8 / (NPIX/8);
    float s[8];
    float b = bias[oc];
    #pragma unroll
    for (int k = 0; k < 8; ++k) s[k] = b;
    #pragma unroll
    for (int qq = 0; qq < 4; ++qq) {
        s16x8 v = *(const s16x8*)(part + (size_t)qq*(128*NPIX) + (size_t)i8*8);
        #pragma unroll
        for (int k = 0; k < 8; ++k) s[k] += bf2f((unsigned short)v[k]);
    }
    f32x4* o = (f32x4*)(out + (size_t)i8*8);
    o[0] = (f32x4){s[0], s[1], s[2], s[3]};
    o[1] = (f32x4){s[4], s[5], s[6], s[7]};
}

// ---------------------------------------------------------------------------
extern "C" void kernel_launch(void* const* d_in, const int* in_sizes, int n_in,
                              void* d_out, int out_size, void* d_ws, size_t ws_size,
                              hipStream_t stream)
{
    const float* cam_feat = (const float*)d_in[0];
    const float* ego2cam  = (const float*)d_in[1];
    const float* conv_w   = (const float*)d_in[2];
    const float* conv_b   = (const float*)d_in[3];
    const int*   img_h    = (const int*)d_in[4];
    const int*   img_w    = (const int*)d_in[5];
    float* out = (float*)d_out;

    // ws: camt f32 34.6MB | feat bf16 40.3MB | wbf bf16 1.7MB.
    // Partials (bf16, 29.5MB) alias camt (dead after proj).
    float* camt = (float*)d_ws;
    bf16* feat = (bf16*)(camt + (size_t)NCAM*CH*FH*FW);
    bf16* wbf  = feat + (size_t)FROWS*FCOLS*CINP;
    bf16* part = (bf16*)d_ws;

    transpose_kernel<<<dim3(6, FH, NCAM), 256, 0, stream>>>(cam_feat, camt);
    wprep_kernel<<<(128*CINP + 255)/256, 256, 0, stream>>>(conv_w, wbf);
    border_kernel<<<724, 128, 0, stream>>>(feat);
    proj_kernel<<<NPIX/4, 256, 0, stream>>>(camt, ego2cam, img_h, img_w, feat);
    conv_mfma_kernel<<<dim3(15, 15, 4), 256, 0, stream>>>(feat, wbf, part);
    combine_kernel<<<(128*NPIX/8 + 255)/256, 256, 0, stream>>>(part, conv_b, out);
}